// Round 7
// baseline (168.398 us; speedup 1.0000x reference)
//
#include <hip/hip_runtime.h>

#define F_IN 165
#define HID  32
#define TROWS 32                        // rows per tile; N=500000 = 32*15625 exact
#define XBYTES (TROWS * F_IN * 4)       // 21120
#define XUNITS 21                       // ceil(21120/1024); unit 20 overreads 384B
#define HCBYTES (TROWS * HID * 4)       // 4096
#define HOFF   (XUNITS * 1024)          // 21504
#define COFF   (HOFF + HCBYTES)         // 25600
#define BUFSZ  (COFF + HCBYTES)         // 29696
#define RING   3
#define PYOFF  (RING * BUFSZ)           // 89088; +512 py -> 89600 B LDS

typedef __attribute__((ext_vector_type(8))) __bf16 bf16x8;
typedef __attribute__((ext_vector_type(4))) float  f32x4;

typedef __attribute__((address_space(1))) void as1_void;
typedef __attribute__((address_space(3))) void as3_void;

__device__ __forceinline__ void gload_lds16(const void* g, void* l) {
    __builtin_amdgcn_global_load_lds(
        reinterpret_cast<as1_void*>(reinterpret_cast<uintptr_t>(g)),
        reinterpret_cast<as3_void*>((uint32_t)reinterpret_cast<uintptr_t>(l)),
        16, 0, 0);
}

__device__ __forceinline__ float fast_sigmoid(float x) {
    return __builtin_amdgcn_rcpf(1.f + __builtin_amdgcn_exp2f(-1.4426950408889634f * x));
}
__device__ __forceinline__ float fast_tanh(float x) {
    return 1.f - 2.f * __builtin_amdgcn_rcpf(1.f + __builtin_amdgcn_exp2f(2.8853900817779268f * x));
}

// ---- workspace (prepacked): frag table 56 slots x 64 lanes x 16B; bias at +57344
#define FRAG_BYTES 57344

struct PrepParams {
    const float *W0, *W1, *W2, *W3;
    const float *Wc0, *Wc1, *Wc2, *Wc3;
    const float *b0, *b1, *b2, *b3;
    const float *bc0, *bc1, *bc2, *bc3;
    char* ws;
};

__global__ void gclstm_prep(PrepParams pp) {
    int t = blockIdx.x * 256 + threadIdx.x;
    if (t < 56 * 64) {
        int slot = t >> 6, l = t & 63;
        int ks = slot >> 3, g = (slot >> 1) & 3, hf = slot & 1;
        int cl = l & 15, q = l >> 4;
        const float* W = (ks < 6)
            ? (g==0 ? pp.W0  : g==1 ? pp.W1  : g==2 ? pp.W2  : pp.W3)
            : (g==0 ? pp.Wc0 : g==1 ? pp.Wc1 : g==2 ? pp.Wc2 : pp.Wc3);
        bf16x8 v;
#pragma unroll
        for (int j = 0; j < 8; ++j) {
            float f = 0.f;
            if (ks < 6) {
                int k = ks * 32 + q * 8 + j;
                if (k < F_IN) f = W[k * HID + hf * 16 + cl];
            } else {
                int k = q * 8 + j;
                f = W[k * HID + hf * 16 + cl];
            }
            v[j] = (__bf16)f;
        }
        *(bf16x8*)(pp.ws + slot * 1024 + l * 16) = v;
    } else if (t < 56 * 64 + 128) {
        int i = t - 56 * 64;
        int g = i >> 5, col = i & 31;
        const float* B  = g==0 ? pp.b0  : g==1 ? pp.b1  : g==2 ? pp.b2  : pp.b3;
        const float* Bc = g==0 ? pp.bc0 : g==1 ? pp.bc1 : g==2 ? pp.bc2 : pp.bc3;
        ((float*)(pp.ws + FRAG_BYTES))[i] = B[col] + Bc[col];
    }
}

struct Params {
    const float *x, *h, *c, *Wl, *bl;
    const char* ws;
    float *y, *h0o, *c0o;
    int n, nt;
};

// Stage one 32-row tile into ring slot. Waves 0-2: 7 x-units each (S=7);
// wave 3: 4 h + 4 c units (S=8). Unit counts are per-wave UNIFORM across
// iterations (dummy staging keeps it so in the tail).
__device__ __forceinline__ void stage_tile(const Params& p, char* smem, int slot,
                                           int tt, int w, int l, bool last) {
    char* buf = smem + slot * BUFSZ;
    if (w < 3) {
        const char* xc = (const char*)p.x + (size_t)tt * XBYTES + (size_t)l * 16;
#pragma unroll
        for (int i = 0; i < 7; ++i) {
            int u = w * 7 + i;
            // unit 20 overreads 384B into the next tile's x (harmless) except
            // on the true last tile: mask lanes >= 40 (rows >= 32, never read).
            if (u != 20 || !last || l < 40)
                gload_lds16(xc + u * 1024, buf + u * 1024);
        }
    } else {
        const char* hc = (const char*)p.h + (size_t)tt * HCBYTES + (size_t)l * 16;
        const char* cc = (const char*)p.c + (size_t)tt * HCBYTES + (size_t)l * 16;
#pragma unroll
        for (int i = 0; i < 4; ++i) {
            gload_lds16(hc + i * 1024, buf + HOFF + i * 1024);
            gload_lds16(cc + i * 1024, buf + COFF + i * 1024);
        }
    }
}

// 256 thr = 4 waves = {sub rows-half} x {hf cols-half}. 3-slot LDS ring,
// depth-2 prefetch: stage(t+2) issued before consuming t. Per-wave vmem ops
// per iter = S stage-units + 9 stores -> "stage(t) complete" == leave 2S+18
// outstanding: vmcnt(32) waves 0-2, vmcnt(34) wave 3 (in-order completion).
__global__ __launch_bounds__(256, 1) void gclstm_main(Params p) {
    __shared__ char smem[PYOFF + 512];
    float* py = (float*)(smem + PYOFF);   // [subwave 0..3][16 rows][2 cls]

    const int tid = threadIdx.x;
    const int w   = tid >> 6;
    const int sub = w >> 1, hf = w & 1;
    const int l   = tid & 63;
    const int cl  = l & 15, q = l >> 4;
    const int col = hf * 16 + cl;

    // weight fragments: this hf, all 4 gates (28 coalesced dwordx4)
    bf16x8 bw[4][7];
#pragma unroll
    for (int ks = 0; ks < 7; ++ks)
#pragma unroll
        for (int g = 0; g < 4; ++g)
            bw[g][ks] = *(const bf16x8*)(p.ws + (ks * 8 + g * 2 + hf) * 1024 + l * 16);

    const float* biasT = (const float*)(p.ws + FRAG_BYTES);
    float bias[4];
#pragma unroll
    for (int g = 0; g < 4; ++g) bias[g] = biasT[g * 32 + col];
    const float wl0 = p.Wl[col * 2 + 0];
    const float wl1 = p.Wl[col * 2 + 1];
    const float bl0 = p.bl[0], bl1 = p.bl[1];

    const int nt = p.nt, stride = gridDim.x;
    int t = blockIdx.x;
    if (t >= nt) return;

    // ---- prologue: stage t and t+1, drain once (establishes count invariant)
    stage_tile(p, smem, 0, t, w, l, t == nt - 1);
    {
        int t1 = t + stride;
        stage_tile(p, smem, 1, t1 < nt ? t1 : 0, w, l, t1 == nt - 1);
    }
    asm volatile("s_waitcnt vmcnt(0)" ::: "memory");

    int cur = 0;
    while (true) {
        // ---- stage t+2 into the slot consumed last iteration ----
        {
            int t2 = t + 2 * stride;
            stage_tile(p, smem, (cur + 2) % RING, t2 < nt ? t2 : 0, w, l, t2 == nt - 1);
        }
        // ---- wait for OWN stage(t) units, then barrier for cross-wave vis ----
        if (w == 3) asm volatile("s_waitcnt vmcnt(34)" ::: "memory");
        else        asm volatile("s_waitcnt vmcnt(32)" ::: "memory");
        __builtin_amdgcn_s_barrier();
        asm volatile("" ::: "memory");

        // ---- consume buf[cur] ----
        const char*  buf = smem + cur * BUFSZ;
        const float* xb  = (const float*)buf;
        const float* hb  = (const float*)(buf + HOFF);
        const float* cb  = (const float*)(buf + COFF);
        const int lrow = sub * 16 + cl;
        const int rb   = lrow * F_IN;

        bf16x8 af[7];
#pragma unroll
        for (int ks = 0; ks < 5; ++ks) {
            float v[8];
#pragma unroll
            for (int j = 0; j < 8; ++j) v[j] = xb[rb + ks * 32 + q * 8 + j];
#pragma unroll
            for (int j = 0; j < 8; ++j) af[ks][j] = (__bf16)v[j];
        }
        {   // ks=5 tail: k=160..164 on q==0 lanes; mask others (stale-LDS safety)
            bool qz = (q == 0);
            float t0 = xb[rb + 160], t1 = xb[rb + 161], t2 = xb[rb + 162];
            float t3 = xb[rb + 163], t4 = xb[rb + 164];
            af[5][0] = (__bf16)(qz ? t0 : 0.f);
            af[5][1] = (__bf16)(qz ? t1 : 0.f);
            af[5][2] = (__bf16)(qz ? t2 : 0.f);
            af[5][3] = (__bf16)(qz ? t3 : 0.f);
            af[5][4] = (__bf16)(qz ? t4 : 0.f);
            af[5][5] = (__bf16)0.f; af[5][6] = (__bf16)0.f; af[5][7] = (__bf16)0.f;
        }
        {   // h fragment
            const float* hr = hb + lrow * HID + q * 8;
            float4 hA = *(const float4*)hr;
            float4 hB = *(const float4*)(hr + 4);
            af[6][0]=(__bf16)hA.x; af[6][1]=(__bf16)hA.y; af[6][2]=(__bf16)hA.z; af[6][3]=(__bf16)hA.w;
            af[6][4]=(__bf16)hB.x; af[6][5]=(__bf16)hB.y; af[6][6]=(__bf16)hB.z; af[6][7]=(__bf16)hB.w;
        }

        f32x4 acc[4];
#pragma unroll
        for (int g = 0; g < 4; ++g) acc[g] = (f32x4){0.f, 0.f, 0.f, 0.f};
#pragma unroll
        for (int ks = 0; ks < 7; ++ks)
#pragma unroll
            for (int g = 0; g < 4; ++g)
                acc[g] = __builtin_amdgcn_mfma_f32_16x16x32_bf16(af[ks], bw[g][ks], acc[g], 0, 0, 0);

        // ---- epilogue: exactly 8 global stores + py LDS writes ----
        const int  drow  = sub * 16 + 4 * q;
        const long gbase = (long)t * TROWS;
#pragma unroll
        for (int jj = 0; jj < 4; ++jj) {
            float iv = fast_sigmoid(acc[0][jj] + bias[0]);
            float fv = fast_sigmoid(acc[1][jj] + bias[1]);
            float gv = fast_tanh   (acc[2][jj] + bias[2]);
            float ov = fast_sigmoid(acc[3][jj] + bias[3]);
            float cvv = cb[(drow + jj) * HID + col];
            float c0 = fv * cvv + iv * gv;
            float h0 = ov * fast_tanh(c0);
            long grow = gbase + drow + jj;
            p.c0o[grow * HID + col] = c0;
            p.h0o[grow * HID + col] = h0;
            float rl = fmaxf(h0, 0.f);
            float r0 = rl * wl0, r1 = rl * wl1;
            r0 += __shfl_xor(r0, 1); r0 += __shfl_xor(r0, 2);
            r0 += __shfl_xor(r0, 4); r0 += __shfl_xor(r0, 8);
            r1 += __shfl_xor(r1, 1); r1 += __shfl_xor(r1, 2);
            r1 += __shfl_xor(r1, 4); r1 += __shfl_xor(r1, 8);
            if (cl == 0) {
                py[((sub * 2 + hf) * 16 + 4 * q + jj) * 2 + 0] = r0;
                py[((sub * 2 + hf) * 16 + 4 * q + jj) * 2 + 1] = r1;
            }
        }
        asm volatile("s_waitcnt lgkmcnt(0)" ::: "memory");
        __builtin_amdgcn_s_barrier();   // B2: py ready + slot-reuse protection
        asm volatile("" ::: "memory");

        // ---- y: wave w stores values v = w*16 + l (1 store per wave) ----
        if (l < 16) {
            int v = w * 16 + l;
            int r = v >> 1, k = v & 1;
            int s2 = r >> 4, r16 = r & 15;
            float yv = py[((s2 * 2 + 0) * 16 + r16) * 2 + k]
                     + py[((s2 * 2 + 1) * 16 + r16) * 2 + k]
                     + (k ? bl1 : bl0);
            p.y[gbase * 2 + v] = yv;
        }

        t += stride;
        if (t >= nt) break;
        cur = (cur + 1) % RING;
    }
}

extern "C" void kernel_launch(void* const* d_in, const int* in_sizes, int n_in,
                              void* d_out, int out_size, void* d_ws, size_t ws_size,
                              hipStream_t stream) {
    PrepParams pp;
    pp.W0  = (const float*)d_in[5];
    pp.W1  = (const float*)d_in[6];
    pp.W2  = (const float*)d_in[7];
    pp.W3  = (const float*)d_in[8];
    pp.b0  = (const float*)d_in[9];
    pp.b1  = (const float*)d_in[10];
    pp.b2  = (const float*)d_in[11];
    pp.b3  = (const float*)d_in[12];
    pp.Wc0 = (const float*)d_in[13];
    pp.Wc1 = (const float*)d_in[14];
    pp.Wc2 = (const float*)d_in[15];
    pp.Wc3 = (const float*)d_in[16];
    pp.bc0 = (const float*)d_in[17];
    pp.bc1 = (const float*)d_in[18];
    pp.bc2 = (const float*)d_in[19];
    pp.bc3 = (const float*)d_in[20];
    pp.ws  = (char*)d_ws;
    hipLaunchKernelGGL(gclstm_prep, dim3(15), dim3(256), 0, stream, pp);

    Params p;
    p.x  = (const float*)d_in[0];
    p.h  = (const float*)d_in[3];
    p.c  = (const float*)d_in[4];
    p.Wl = (const float*)d_in[21];
    p.bl = (const float*)d_in[22];
    p.ws = (const char*)d_ws;

    const int n = in_sizes[0] / F_IN;   // 500000 (divisible by TROWS)
    p.n  = n;
    p.nt = n / TROWS;                   // 15625

    float* out = (float*)d_out;
    p.y   = out;
    p.h0o = out + (long)n * 2;
    p.c0o = out + (long)n * 2 + (long)n * HID;

    hipLaunchKernelGGL(gclstm_main, dim3(256), dim3(256), 0, stream, p);
}

// Round 8
// 157.193 us; speedup vs baseline: 1.0713x; 1.0713x over previous
//
#include <hip/hip_runtime.h>

#define F_IN 165
#define HID  32
#define TROWS 16                        // rows per tile; N=500000 = 16*31250 exact
#define XBYTES (TROWS * F_IN * 4)       // 10560
#define XUNITS 11                       // unit 10 overreads 704B into next tile
#define HCBYTES (TROWS * HID * 4)       // 2048
#define HOFF   (XUNITS * 1024)          // 11264
#define COFF   (HOFF + HCBYTES)         // 13312
#define BUFSZ  (COFF + HCBYTES)         // 15360
#define PYOFF  (2 * BUFSZ)              // 30720; +256 py -> 30976 B LDS

typedef __attribute__((ext_vector_type(8))) __bf16 bf16x8;
typedef __attribute__((ext_vector_type(4))) float  f32x4;

typedef __attribute__((address_space(1))) void as1_void;
typedef __attribute__((address_space(3))) void as3_void;

__device__ __forceinline__ void gload_lds16(const void* g, void* l) {
    __builtin_amdgcn_global_load_lds(
        reinterpret_cast<as1_void*>(reinterpret_cast<uintptr_t>(g)),
        reinterpret_cast<as3_void*>((uint32_t)reinterpret_cast<uintptr_t>(l)),
        16, 0, 0);
}

__device__ __forceinline__ float fast_sigmoid(float x) {
    return __builtin_amdgcn_rcpf(1.f + __builtin_amdgcn_exp2f(-1.4426950408889634f * x));
}
__device__ __forceinline__ float fast_tanh(float x) {
    return 1.f - 2.f * __builtin_amdgcn_rcpf(1.f + __builtin_amdgcn_exp2f(2.8853900817779268f * x));
}

// ---- workspace (prepacked): frag table 56 slots x 64 lanes x 16B; bias at +57344
#define FRAG_BYTES 57344

struct PrepParams {
    const float *W0, *W1, *W2, *W3;
    const float *Wc0, *Wc1, *Wc2, *Wc3;
    const float *b0, *b1, *b2, *b3;
    const float *bc0, *bc1, *bc2, *bc3;
    char* ws;
};

__global__ void gclstm_prep(PrepParams pp) {
    int t = blockIdx.x * 256 + threadIdx.x;
    if (t < 56 * 64) {
        int slot = t >> 6, l = t & 63;
        int ks = slot >> 3, g = (slot >> 1) & 3, hf = slot & 1;
        int cl = l & 15, q = l >> 4;
        const float* W = (ks < 6)
            ? (g==0 ? pp.W0  : g==1 ? pp.W1  : g==2 ? pp.W2  : pp.W3)
            : (g==0 ? pp.Wc0 : g==1 ? pp.Wc1 : g==2 ? pp.Wc2 : pp.Wc3);
        bf16x8 v;
#pragma unroll
        for (int j = 0; j < 8; ++j) {
            float f = 0.f;
            if (ks < 6) {
                int k = ks * 32 + q * 8 + j;
                if (k < F_IN) f = W[k * HID + hf * 16 + cl];
            } else {
                int k = q * 8 + j;
                f = W[k * HID + hf * 16 + cl];
            }
            v[j] = (__bf16)f;
        }
        *(bf16x8*)(pp.ws + slot * 1024 + l * 16) = v;
    } else if (t < 56 * 64 + 128) {
        int i = t - 56 * 64;
        int g = i >> 5, col = i & 31;
        const float* B  = g==0 ? pp.b0  : g==1 ? pp.b1  : g==2 ? pp.b2  : pp.b3;
        const float* Bc = g==0 ? pp.bc0 : g==1 ? pp.bc1 : g==2 ? pp.bc2 : pp.bc3;
        ((float*)(pp.ws + FRAG_BYTES))[i] = B[col] + Bc[col];
    }
}

struct Params {
    const float *x, *h, *c, *Wl, *bl;
    const char* ws;
    float *y, *h0o, *c0o;
    int n, nt;
};

// Stage one 16-row tile into slot. Wave0: x units 0-6 (7 ops); wave1: x units
// 7-10 (4) + h 2 + c 2 (8 ops). h/c use PRE-SWIZZLED GLOBAL SOURCE (rule #21):
// LDS dest linear; src byte = row*128 + (off ^ ((row&7)<<4)) so reads with the
// same XOR are conflict-reduced. Per-wave op counts uniform across iters.
__device__ __forceinline__ void stage_tile(const Params& p, char* smem, int slot,
                                           int tt, int w, int l, bool last) {
    char* buf = smem + slot * BUFSZ;
    const char* xc = (const char*)p.x + (size_t)tt * XBYTES + (size_t)l * 16;
    if (w == 0) {
#pragma unroll
        for (int i = 0; i < 7; ++i)
            gload_lds16(xc + i * 1024, buf + i * 1024);
    } else {
#pragma unroll
        for (int i = 7; i < 11; ++i) {
            // unit 10 overreads 704B into next tile's x (harmless) except on
            // the true last tile: mask lanes >= 20 (bytes >= 10560).
            if (i != 10 || !last || l < 20)
                gload_lds16(xc + i * 1024, buf + i * 1024);
        }
        const int r = l >> 3;            // row low bits (0..7)
        const int o = (l & 7) * 16;      // 16B offset within 128B row
        const int osw = o ^ (r << 4);    // swizzled source offset
        const char* hb = (const char*)p.h + (size_t)tt * HCBYTES;
        const char* cc = (const char*)p.c + (size_t)tt * HCBYTES;
#pragma unroll
        for (int i = 0; i < 2; ++i) {
            int srcoff = (i * 8 + r) * 128 + osw;
            gload_lds16(hb + srcoff, buf + HOFF + i * 1024 + l * 16);
            gload_lds16(cc + srcoff, buf + COFF + i * 1024 + l * 16);
        }
    }
}

// 128 thr = 2 waves = 2 hf col-halves; each wave: 16 rows x 16 cols x 4 gates.
// Depth-1 double-buffer (proven R5 bookkeeping): stage(t+1) issued before
// consume(t); exactly 9 stores/wave/iter -> end-of-iter vmcnt(9) waits
// precisely for the staging. 5 blocks/CU (31KB LDS) = 10 waves/CU.
__global__ __launch_bounds__(128, 2) void gclstm_main(Params p) {
    __shared__ char smem[PYOFF + 256];
    float* py = (float*)(smem + PYOFF);   // [hf][16 rows][2 cls]

    const int tid = threadIdx.x;
    const int w   = tid >> 6;             // wave id == hf
    const int l   = tid & 63;
    const int cl  = l & 15, q = l >> 4;
    const int col = w * 16 + cl;

    // weight fragments: this hf, all 4 gates (28 coalesced dwordx4)
    bf16x8 bw[4][7];
#pragma unroll
    for (int ks = 0; ks < 7; ++ks)
#pragma unroll
        for (int g = 0; g < 4; ++g)
            bw[g][ks] = *(const bf16x8*)(p.ws + (ks * 8 + g * 2 + w) * 1024 + l * 16);

    const float* biasT = (const float*)(p.ws + FRAG_BYTES);
    float bias[4];
#pragma unroll
    for (int g = 0; g < 4; ++g) bias[g] = biasT[g * 32 + col];
    const float wl0 = p.Wl[col * 2 + 0];
    const float wl1 = p.Wl[col * 2 + 1];
    const float bl0 = p.bl[0], bl1 = p.bl[1];

    const int nt = p.nt, stride = gridDim.x;
    int t = blockIdx.x;
    if (t >= nt) return;

    // prologue: stage first tile, drain once, make visible
    stage_tile(p, smem, 0, t, w, l, t == nt - 1);
    asm volatile("s_waitcnt vmcnt(0)" ::: "memory");
    __builtin_amdgcn_s_barrier();
    asm volatile("" ::: "memory");

    int cur = 0;
    while (true) {
        const int tn = t + stride;
        const bool more = (tn < nt);
        if (more) stage_tile(p, smem, cur ^ 1, tn, w, l, tn == nt - 1);  // prefetch

        // ---- consume buf[cur] ----
        const char*  buf = smem + cur * BUFSZ;
        const float* xb  = (const float*)buf;
        const int rb = cl * F_IN;

        bf16x8 af[7];
#pragma unroll
        for (int ks = 0; ks < 5; ++ks) {
            float v[8];
#pragma unroll
            for (int j = 0; j < 8; ++j) v[j] = xb[rb + ks * 32 + q * 8 + j];
#pragma unroll
            for (int j = 0; j < 8; ++j) af[ks][j] = (__bf16)v[j];
        }
        {   // ks=5 tail: k=160..164 on q==0 lanes; mask others
            bool qz = (q == 0);
            float t0 = xb[rb + 160], t1 = xb[rb + 161], t2 = xb[rb + 162];
            float t3 = xb[rb + 163], t4 = xb[rb + 164];
            af[5][0] = (__bf16)(qz ? t0 : 0.f);
            af[5][1] = (__bf16)(qz ? t1 : 0.f);
            af[5][2] = (__bf16)(qz ? t2 : 0.f);
            af[5][3] = (__bf16)(qz ? t3 : 0.f);
            af[5][4] = (__bf16)(qz ? t4 : 0.f);
            af[5][5] = (__bf16)0.f; af[5][6] = (__bf16)0.f; af[5][7] = (__bf16)0.f;
        }
        {   // h fragment: swizzled reads (row = cl)
            const int s  = (cl & 7) << 4;
            const char* hrow = buf + HOFF + cl * 128;
            float4 hA = *(const float4*)(hrow + ((q * 32)      ^ s));
            float4 hB = *(const float4*)(hrow + ((q * 32 + 16) ^ s));
            af[6][0]=(__bf16)hA.x; af[6][1]=(__bf16)hA.y; af[6][2]=(__bf16)hA.z; af[6][3]=(__bf16)hA.w;
            af[6][4]=(__bf16)hB.x; af[6][5]=(__bf16)hB.y; af[6][6]=(__bf16)hB.z; af[6][7]=(__bf16)hB.w;
        }

        f32x4 acc[4];
#pragma unroll
        for (int g = 0; g < 4; ++g) acc[g] = (f32x4){0.f, 0.f, 0.f, 0.f};
#pragma unroll
        for (int ks = 0; ks < 7; ++ks)
#pragma unroll
            for (int g = 0; g < 4; ++g)
                acc[g] = __builtin_amdgcn_mfma_f32_16x16x32_bf16(af[ks], bw[g][ks], acc[g], 0, 0, 0);

        // ---- epilogue: exactly 8 global stores + py LDS writes ----
        const long gbase = (long)t * TROWS;
#pragma unroll
        for (int jj = 0; jj < 4; ++jj) {
            const int r = 4 * q + jj;    // D row in tile
            float iv = fast_sigmoid(acc[0][jj] + bias[0]);
            float fv = fast_sigmoid(acc[1][jj] + bias[1]);
            float gv = fast_tanh   (acc[2][jj] + bias[2]);
            float ov = fast_sigmoid(acc[3][jj] + bias[3]);
            float cvv = *(const float*)(buf + COFF + r * 128 + ((col * 4) ^ ((r & 7) << 4)));
            float c0 = fv * cvv + iv * gv;
            float h0 = ov * fast_tanh(c0);
            long grow = gbase + r;
            p.c0o[grow * HID + col] = c0;
            p.h0o[grow * HID + col] = h0;
            float rl = fmaxf(h0, 0.f);
            float r0 = rl * wl0, r1 = rl * wl1;
            r0 += __shfl_xor(r0, 1); r0 += __shfl_xor(r0, 2);
            r0 += __shfl_xor(r0, 4); r0 += __shfl_xor(r0, 8);
            r1 += __shfl_xor(r1, 1); r1 += __shfl_xor(r1, 2);
            r1 += __shfl_xor(r1, 4); r1 += __shfl_xor(r1, 8);
            if (cl == 0) {
                py[(w * 16 + r) * 2 + 0] = r0;
                py[(w * 16 + r) * 2 + 1] = r1;
            }
        }
        asm volatile("s_waitcnt lgkmcnt(0)" ::: "memory");
        __builtin_amdgcn_s_barrier();   // B2: py ready across waves
        asm volatile("" ::: "memory");

        // ---- y: wave w stores values v = w*16 + l (1 store per wave) ----
        if (l < 16) {
            int v = w * 16 + l;
            int r = v >> 1, k = v & 1;
            float yv = py[(0 * 16 + r) * 2 + k] + py[(1 * 16 + r) * 2 + k]
                     + (k ? bl1 : bl0);
            p.y[gbase * 2 + v] = yv;
        }

        if (!more) break;
        // wait: all older than the 9 stores (== this iter's staging) complete
        asm volatile("s_waitcnt vmcnt(9)" ::: "memory");
        __builtin_amdgcn_s_barrier();   // B3: staged visible + py/slot reuse safe
        asm volatile("" ::: "memory");
        cur ^= 1; t = tn;
    }
}

extern "C" void kernel_launch(void* const* d_in, const int* in_sizes, int n_in,
                              void* d_out, int out_size, void* d_ws, size_t ws_size,
                              hipStream_t stream) {
    PrepParams pp;
    pp.W0  = (const float*)d_in[5];
    pp.W1  = (const float*)d_in[6];
    pp.W2  = (const float*)d_in[7];
    pp.W3  = (const float*)d_in[8];
    pp.b0  = (const float*)d_in[9];
    pp.b1  = (const float*)d_in[10];
    pp.b2  = (const float*)d_in[11];
    pp.b3  = (const float*)d_in[12];
    pp.Wc0 = (const float*)d_in[13];
    pp.Wc1 = (const float*)d_in[14];
    pp.Wc2 = (const float*)d_in[15];
    pp.Wc3 = (const float*)d_in[16];
    pp.bc0 = (const float*)d_in[17];
    pp.bc1 = (const float*)d_in[18];
    pp.bc2 = (const float*)d_in[19];
    pp.bc3 = (const float*)d_in[20];
    pp.ws  = (char*)d_ws;
    hipLaunchKernelGGL(gclstm_prep, dim3(15), dim3(256), 0, stream, pp);

    Params p;
    p.x  = (const float*)d_in[0];
    p.h  = (const float*)d_in[3];
    p.c  = (const float*)d_in[4];
    p.Wl = (const float*)d_in[21];
    p.bl = (const float*)d_in[22];
    p.ws = (const char*)d_ws;

    const int n = in_sizes[0] / F_IN;   // 500000 (divisible by TROWS)
    p.n  = n;
    p.nt = n / TROWS;                   // 31250

    float* out = (float*)d_out;
    p.y   = out;
    p.h0o = out + (long)n * 2;
    p.c0o = out + (long)n * 2 + (long)n * HID;

    // grid = 5 blocks/CU x 256 CUs (LDS-bound residency), grid-stride the rest
    hipLaunchKernelGGL(gclstm_main, dim3(1280), dim3(128), 0, stream, p);
}